// Round 5
// baseline (259.300 us; speedup 1.0000x reference)
//
#include <hip/hip_runtime.h>
#include <math.h>

// MultiHeadAttention_3728031613617 — bf16-MFMA pipeline v5.
// B=8, S=2048, D=512, head=64, heads=8 (identical heads => compute once).
// out = (softmax(0.1*(xWq)(xWk)^T) @ (xWv)) @ dr, dr[j,o] = sum_h dense[h*64+j,o]
//
// v5 = round-2's winning flash structure (wave-private LDS staging, barrier-
// free main loop, Q-tile 16, grid 1024 = 4 blocks/CU = 16 waves/CU) with:
//  - XOR chunk-swizzled LDS (kills round-2's 16-way conflicts at ZERO LDS
//    growth: block stays 38912 B; padding would drop to 3 blocks/CU)
//  - register prefetch of next K/V tile (round-3's addition, now at the
//    right occupancy)
//  - fused dense epilogue writing full 2KB out rows per block (L2 merge).

typedef __bf16 bf16;
typedef __bf16 bf16x4v __attribute__((ext_vector_type(4)));
typedef __bf16 bf16x8v __attribute__((ext_vector_type(8)));
typedef float f32x4 __attribute__((ext_vector_type(4)));

namespace {
constexpr int kS = 2048;
constexpr int kD = 512;
constexpr int kRows = 16384;  // 8 * 2048
}

#define MFMA16(a, b, c) __builtin_amdgcn_mfma_f32_16x16x32_bf16((a), (b), (c), 0, 0, 0)

// ---------------------------------------------------------------------------
// Kernel 0: prep. wtg[mat][n=64][k=512] = (bf16)W[mat][k][n]
//           drt[o=512][j=64] = (bf16) sum_h dense[h*64+j, o]
// ---------------------------------------------------------------------------
__global__ __launch_bounds__(256) void prep_kernel(const float* __restrict__ w,
                                                   const float* __restrict__ dense,
                                                   bf16* __restrict__ wtg,
                                                   bf16* __restrict__ drt) {
  int idx = blockIdx.x * 256 + threadIdx.x;  // < 131072
  if (idx < 98304) {
    int mat = idx >> 15, rem = idx & 32767;
    int n = rem >> 9, k = rem & 511;
    wtg[idx] = (bf16)w[mat * 32768 + k * 64 + n];
  } else {
    int e = idx - 98304;  // < 32768
    int o = e >> 6, j = e & 63;
    float s = 0.f;
#pragma unroll
    for (int h = 0; h < 8; ++h) s += dense[(size_t)(h * 64 + j) * kD + o];
    drt[e] = (bf16)s;  // [o][j]
  }
}

// ---------------------------------------------------------------------------
// Kernel 1: fused QKV projection (x read ONCE). grid 256, block 256.
// wq[row][64], wk[row][64], wvt[64][16384] (coalesced via LDS transpose).
// ---------------------------------------------------------------------------
__global__ __launch_bounds__(256) void proj_kernel(const float* __restrict__ x,
                                                   const bf16* __restrict__ wtg,
                                                   bf16* __restrict__ wq,
                                                   bf16* __restrict__ wk,
                                                   bf16* __restrict__ wvt) {
  const int bt = blockIdx.x;
  const int tid = threadIdx.x;
  const int w = tid >> 6, tx = tid & 15, quad = (tid >> 4) & 3;
  const int row0 = bt * 64;

  __shared__ bf16 Xs[64 * 72];       // stride 72 (pad)
  __shared__ bf16 Wts[3 * 64 * 72];

  f32x4 acc[3][4];
#pragma unroll
  for (int m = 0; m < 3; ++m)
#pragma unroll
    for (int nt = 0; nt < 4; ++nt) acc[m][nt] = (f32x4){0.f, 0.f, 0.f, 0.f};

  for (int k0 = 0; k0 < kD; k0 += 64) {
    __syncthreads();
#pragma unroll
    for (int p = 0; p < 4; ++p) {
      int i4 = tid + p * 256;
      int r = i4 >> 4, c4 = (i4 & 15) * 4;
      float4 f = *(const float4*)&x[(size_t)(row0 + r) * kD + k0 + c4];
      bf16x4v h = {(bf16)f.x, (bf16)f.y, (bf16)f.z, (bf16)f.w};
      *(bf16x4v*)&Xs[r * 72 + c4] = h;
    }
#pragma unroll
    for (int p = 0; p < 6; ++p) {
      int cc = tid + p * 256;
      int mat = cc >> 9, rem = cc & 511;
      int n = rem >> 3, c8 = (rem & 7) * 8;
      *(uint4*)&Wts[(mat * 64 + n) * 72 + c8] =
          *(const uint4*)&wtg[(size_t)mat * 32768 + (size_t)n * 512 + k0 + c8];
    }
    __syncthreads();
#pragma unroll
    for (int s = 0; s < 2; ++s) {
      bf16x8v a = *(bf16x8v*)&Xs[(w * 16 + tx) * 72 + s * 32 + quad * 8];
#pragma unroll
      for (int m = 0; m < 3; ++m)
#pragma unroll
        for (int nt = 0; nt < 4; ++nt) {
          bf16x8v bfr =
              *(bf16x8v*)&Wts[(m * 64 + nt * 16 + tx) * 72 + s * 32 + quad * 8];
          acc[m][nt] = MFMA16(a, bfr, acc[m][nt]);
        }
    }
  }

#pragma unroll
  for (int nt = 0; nt < 4; ++nt)
#pragma unroll
    for (int r = 0; r < 4; ++r) {
      int row_g = row0 + w * 16 + quad * 4 + r;
      int col = nt * 16 + tx;
      wq[(size_t)row_g * 64 + col] = (bf16)acc[0][nt][r];
      wk[(size_t)row_g * 64 + col] = (bf16)acc[1][nt][r];
    }
  // V: transpose in LDS, coalesced 128B-per-row stores
  __syncthreads();
  bf16* Vt = Xs;
#pragma unroll
  for (int nt = 0; nt < 4; ++nt)
#pragma unroll
    for (int r = 0; r < 4; ++r)
      Vt[(nt * 16 + tx) * 72 + (w * 16 + quad * 4 + r)] = (bf16)acc[2][nt][r];
  __syncthreads();
#pragma unroll
  for (int p = 0; p < 2; ++p) {
    int c = tid + p * 256;
    int v = c >> 3, seg = c & 7;
    *(uint4*)&wvt[(size_t)v * kRows + row0 + seg * 8] =
        *(uint4*)&Vt[v * 72 + seg * 8];
  }
}

// ---------------------------------------------------------------------------
// Kernel 2: flash attention + fused dense epilogue, v5.
// grid 1024: b = bid&7 (XCD affinity), qb = bid>>3 (16 Q-rows). Block 256 =
// 4 waves; wave w owns 32-key tiles (t*4+w)*32, t<16. Barrier-free main loop,
// wave-private swizzled LDS, register prefetch of next tile.
// LDS (38912 B -> 4 blocks/CU):
//   [0,2048)        Qs 16x64 (row-xor-swizzled)  | epilogue reuses region
//   [2048,18432)    Ksw 4 x (32x64 swizzled)     |   Osh 16x66 f32 @2048
//   [18432,34816)   Vtw 4 x (64x32 swizzled)     |   Lsh 16 f32   @6272
//   [34816,38912)   Psw 4 x (16x32 swizzled)     |   vob 16x64    @6400
// ---------------------------------------------------------------------------
__global__ __launch_bounds__(256, 4) void flash_kernel(
    const bf16* __restrict__ wq, const bf16* __restrict__ wk,
    const bf16* __restrict__ wvt, const bf16* __restrict__ drt,
    float* __restrict__ out) {
  const int bid = blockIdx.x;
  const int b = bid & 7, qb = bid >> 3;
  const int q0 = qb * 16;
  const int tid = threadIdx.x;
  const int w = tid >> 6, lane = tid & 63, tx = tid & 15, quad = (tid >> 4) & 3;

  __shared__ __align__(16) char lds[38912];
  bf16* Qs = (bf16*)lds;
  bf16* Ksw = (bf16*)(lds + 2048 + w * 4096);
  bf16* Vtw = (bf16*)(lds + 18432 + w * 4096);
  bf16* Psw = (bf16*)(lds + 34816 + w * 1024);

  const bf16* wqb = wq + (size_t)(b * kS) * 64;
  const bf16* wkb = wk + (size_t)(b * kS) * 64;
  const bf16* wvb = wvt + b * kS;

  // stage Q (16x64, row-swizzled: chunk c at c^(r&7))
  if (tid < 128) {
    int r = tid >> 3, lc = tid & 7;
    *(uint4*)&Qs[r * 64 + ((lc ^ (r & 7)) * 8)] =
        *(const uint4*)&wqb[(size_t)(q0 + r) * 64 + lc * 8];
  }
  __syncthreads();

  // swizzle helpers (per-lane constants)
  const int h2 = (tx ^ (tx >> 2)) & 3;  // for 32-el rows (V, P) indexed by tx
  // Q/K frag chunk offsets: chunk cc=s*4+quad at ((cc)^(row&7))*8, row%8 = tx&7
  const int kc0 = ((quad) ^ (tx & 7)) * 8;      // s=0
  const int kc1 = ((4 + quad) ^ (tx & 7)) * 8;  // s=1

  bf16x8v aq0 = *(bf16x8v*)&Qs[tx * 64 + kc0];
  bf16x8v aq1 = *(bf16x8v*)&Qs[tx * 64 + kc1];

  f32x4 oacc[4];
#pragma unroll
  for (int nt = 0; nt < 4; ++nt) oacc[nt] = (f32x4){0.f, 0.f, 0.f, 0.f};
  float lsum[4] = {0.f, 0.f, 0.f, 0.f};

  // staging-store lane constants
  const int ksr = lane >> 3, kslc = lane & 7;          // K: 8 lanes/row
  const int vsv = lane >> 2, vsck = lane & 3;          // V: 4 lanes/v-row
  // prefetch tile 0
  uint4 kr[4], vr[4];
  {
    const int k0 = w * 32;
#pragma unroll
    for (int j = 0; j < 4; ++j) {
      kr[j] = *(const uint4*)&wkb[(size_t)(k0 + ksr + j * 8) * 64 + kslc * 8];
      vr[j] = *(const uint4*)&wvb[(size_t)(vsv + j * 16) * kRows + k0 + vsck * 8];
    }
  }

  for (int t = 0; t < 16; ++t) {
    // commit staged regs to wave-private swizzled LDS
#pragma unroll
    for (int j = 0; j < 4; ++j) {
      int r = ksr + j * 8;
      *(uint4*)&Ksw[r * 64 + ((kslc ^ (r & 7)) * 8)] = kr[j];
      int v = vsv + j * 16;
      *(uint4*)&Vtw[v * 32 + (((vsck ^ ((v ^ (v >> 2)) & 3)) * 8))] = vr[j];
    }
    // prefetch next tile (stays in flight over the MFMA/exp work)
    if (t < 15) {
      const int k0n = ((t + 1) * 4 + w) * 32;
#pragma unroll
      for (int j = 0; j < 4; ++j) {
        kr[j] = *(const uint4*)&wkb[(size_t)(k0n + ksr + j * 8) * 64 + kslc * 8];
        vr[j] =
            *(const uint4*)&wvb[(size_t)(vsv + j * 16) * kRows + k0n + vsck * 8];
      }
    }

    // QK^T: D[16 q][32 keys]
#pragma unroll
    for (int nt = 0; nt < 2; ++nt) {
      int krow = nt * 16 + tx;
      bf16x8v b0 = *(bf16x8v*)&Ksw[krow * 64 + kc0];
      bf16x8v b1 = *(bf16x8v*)&Ksw[krow * 64 + kc1];
      f32x4 z = (f32x4){0.f, 0.f, 0.f, 0.f};
      z = MFMA16(aq0, b0, z);
      z = MFMA16(aq1, b1, z);
      // no-max softmax numerator + swizzled P store (C-layout -> A-layout)
#pragma unroll
      for (int r = 0; r < 4; ++r) {
        float p = __expf(z[r] * 0.1f);
        lsum[r] += p;
        int q = quad * 4 + r;
        int chunk = nt * 2 + (tx >> 3);
        Psw[q * 32 + ((chunk ^ ((q ^ (q >> 2)) & 3)) * 8) + (tx & 7)] = (bf16)p;
      }
    }

    // PV: O[16 q][64 v] += P[16][32] * V[32][64]
    bf16x8v pa = *(bf16x8v*)&Psw[tx * 32 + ((quad ^ h2) * 8)];
#pragma unroll
    for (int nt = 0; nt < 4; ++nt) {
      bf16x8v vb = *(bf16x8v*)&Vtw[(nt * 16 + tx) * 32 + ((quad ^ h2) * 8)];
      oacc[nt] = MFMA16(pa, vb, oacc[nt]);
    }
  }

  // ---- cross-wave combine (alias Ksw region; zero AFTER loop) ----
  __syncthreads();
  float* Osh = (float*)(lds + 2048);  // 16 x 66 (padded)
  float* Lsh = (float*)(lds + 6272);  // 16
  bf16* vob = (bf16*)(lds + 6400);    // 16 x 64, row-swizzled
  for (int i = tid; i < 16 * 66; i += 256) Osh[i] = 0.f;
  if (tid < 16) Lsh[tid] = 0.f;
  __syncthreads();
#pragma unroll
  for (int nt = 0; nt < 4; ++nt)
#pragma unroll
    for (int r = 0; r < 4; ++r)
      atomicAdd(&Osh[(quad * 4 + r) * 66 + nt * 16 + tx], oacc[nt][r]);
#pragma unroll
  for (int r = 0; r < 4; ++r) {
    float v = lsum[r];
#pragma unroll
    for (int m = 1; m < 16; m <<= 1) v += __shfl_xor(v, m, 64);
    if (tx == 0) atomicAdd(&Lsh[quad * 4 + r], v);
  }
  __syncthreads();
  for (int e = tid; e < 1024; e += 256) {
    int row = e >> 6, col = e & 63;
    vob[row * 64 + (((col >> 3) ^ (row & 7)) * 8) + (col & 7)] =
        (bf16)(Osh[row * 66 + col] / Lsh[row]);
  }
  __syncthreads();

  // ---- fused dense epilogue: out[16 x 512] = vob[16 x 64] @ drt^T ----
  bf16x8v av0 = *(bf16x8v*)&vob[tx * 64 + kc0];
  bf16x8v av1 = *(bf16x8v*)&vob[tx * 64 + kc1];
#pragma unroll
  for (int i = 0; i < 8; ++i) {
    const int ct = w * 8 + i;  // 16-col output tile
    bf16x8v bd0 = *(const bf16x8v*)&drt[(size_t)(ct * 16 + tx) * 64 + quad * 8];
    bf16x8v bd1 =
        *(const bf16x8v*)&drt[(size_t)(ct * 16 + tx) * 64 + 32 + quad * 8];
    f32x4 z = (f32x4){0.f, 0.f, 0.f, 0.f};
    z = MFMA16(av0, bd0, z);
    z = MFMA16(av1, bd1, z);
#pragma unroll
    for (int r = 0; r < 4; ++r)
      out[(size_t)(b * kS + q0 + quad * 4 + r) * kD + ct * 16 + tx] = z[r];
  }
}

extern "C" void kernel_launch(void* const* d_in, const int* in_sizes, int n_in,
                              void* d_out, int out_size, void* d_ws,
                              size_t ws_size, hipStream_t stream) {
  const float* x = (const float*)d_in[0];      // [8,2048,512]
  const float* w = (const float*)d_in[1];      // [3,512,64]
  const float* dense = (const float*)d_in[2];  // [512,512]
  float* out = (float*)d_out;                  // [8,2048,512] fp32

  bf16* wq = (bf16*)d_ws;                // 1,048,576
  bf16* wk = wq + (size_t)kRows * 64;    // 1,048,576
  bf16* wvt = wk + (size_t)kRows * 64;   // 1,048,576  [64][16384]
  bf16* wtg = wvt + (size_t)kRows * 64;  // 98,304     [3][64][512]
  bf16* drt = wtg + 98304;               // 32,768     [512][64]

  prep_kernel<<<512, 256, 0, stream>>>(w, dense, wtg, drt);
  proj_kernel<<<256, 256, 0, stream>>>(x, wtg, wq, wk, wvt);
  flash_kernel<<<1024, 256, 0, stream>>>(wq, wk, wvt, drt, out);
}

// Round 6
// 142.398 us; speedup vs baseline: 1.8209x; 1.8209x over previous
//
#include <hip/hip_runtime.h>
#include <math.h>

// MultiHeadAttention_3728031613617 — bf16-MFMA pipeline v6.
// v6 = round-2's flash structure VERBATIM (the only one measured fast:
// <=42 µs) + the single counter-verified fix from r5 (XOR chunk swizzle,
// conflicts 2.5e7 -> 2.4e6). No reg prefetch, no fused epilogue, no LDS
// atomics — those shipped in every slow round (r3/r4/r5). Separate
// out_gemm (r1/r2's, measured fine). prep/proj kept from r5.

typedef __bf16 bf16;
typedef __bf16 bf16x4v __attribute__((ext_vector_type(4)));
typedef __bf16 bf16x8v __attribute__((ext_vector_type(8)));
typedef float f32x4 __attribute__((ext_vector_type(4)));

namespace {
constexpr int kS = 2048;
constexpr int kD = 512;
constexpr int kH = 64;
constexpr int kRows = 16384;  // 8 * 2048
}

#define MFMA16(a, b, c) __builtin_amdgcn_mfma_f32_16x16x32_bf16((a), (b), (c), 0, 0, 0)

// ---------------------------------------------------------------------------
// Kernel 0: prep. wtg[mat][n=64][k=512] = (bf16)W[mat][k][n]
//           dr[j=64][o=512] = (f32) sum_h dense[h*64+j, o]
// ---------------------------------------------------------------------------
__global__ __launch_bounds__(256) void prep_kernel(const float* __restrict__ w,
                                                   const float* __restrict__ dense,
                                                   bf16* __restrict__ wtg,
                                                   float* __restrict__ dr) {
  int idx = blockIdx.x * 256 + threadIdx.x;  // < 131072
  if (idx < 98304) {
    int mat = idx >> 15, rem = idx & 32767;
    int n = rem >> 9, k = rem & 511;
    wtg[idx] = (bf16)w[mat * 32768 + k * 64 + n];
  } else {
    int e = idx - 98304;  // < 32768
    int j = e >> 9, o = e & 511;
    float s = 0.f;
#pragma unroll
    for (int h = 0; h < 8; ++h) s += dense[(size_t)(h * 64 + j) * kD + o];
    dr[e] = s;  // [j][o] f32
  }
}

// ---------------------------------------------------------------------------
// Kernel 1: fused QKV projection (x read ONCE). grid 256, block 256.
// wq[row][64], wk[row][64], wvt[64][16384] (coalesced via LDS transpose).
// (unchanged from r4/r5 — non-flash pipeline time measured ~24 µs total)
// ---------------------------------------------------------------------------
__global__ __launch_bounds__(256) void proj_kernel(const float* __restrict__ x,
                                                   const bf16* __restrict__ wtg,
                                                   bf16* __restrict__ wq,
                                                   bf16* __restrict__ wk,
                                                   bf16* __restrict__ wvt) {
  const int bt = blockIdx.x;
  const int tid = threadIdx.x;
  const int w = tid >> 6, tx = tid & 15, quad = (tid >> 4) & 3;
  const int row0 = bt * 64;

  __shared__ bf16 Xs[64 * 72];
  __shared__ bf16 Wts[3 * 64 * 72];

  f32x4 acc[3][4];
#pragma unroll
  for (int m = 0; m < 3; ++m)
#pragma unroll
    for (int nt = 0; nt < 4; ++nt) acc[m][nt] = (f32x4){0.f, 0.f, 0.f, 0.f};

  for (int k0 = 0; k0 < kD; k0 += 64) {
    __syncthreads();
#pragma unroll
    for (int p = 0; p < 4; ++p) {
      int i4 = tid + p * 256;
      int r = i4 >> 4, c4 = (i4 & 15) * 4;
      float4 f = *(const float4*)&x[(size_t)(row0 + r) * kD + k0 + c4];
      bf16x4v h = {(bf16)f.x, (bf16)f.y, (bf16)f.z, (bf16)f.w};
      *(bf16x4v*)&Xs[r * 72 + c4] = h;
    }
#pragma unroll
    for (int p = 0; p < 6; ++p) {
      int cc = tid + p * 256;
      int mat = cc >> 9, rem = cc & 511;
      int n = rem >> 3, c8 = (rem & 7) * 8;
      *(uint4*)&Wts[(mat * 64 + n) * 72 + c8] =
          *(const uint4*)&wtg[(size_t)mat * 32768 + (size_t)n * 512 + k0 + c8];
    }
    __syncthreads();
#pragma unroll
    for (int s = 0; s < 2; ++s) {
      bf16x8v a = *(bf16x8v*)&Xs[(w * 16 + tx) * 72 + s * 32 + quad * 8];
#pragma unroll
      for (int m = 0; m < 3; ++m)
#pragma unroll
        for (int nt = 0; nt < 4; ++nt) {
          bf16x8v bfr =
              *(bf16x8v*)&Wts[(m * 64 + nt * 16 + tx) * 72 + s * 32 + quad * 8];
          acc[m][nt] = MFMA16(a, bfr, acc[m][nt]);
        }
    }
  }

#pragma unroll
  for (int nt = 0; nt < 4; ++nt)
#pragma unroll
    for (int r = 0; r < 4; ++r) {
      int row_g = row0 + w * 16 + quad * 4 + r;
      int col = nt * 16 + tx;
      wq[(size_t)row_g * 64 + col] = (bf16)acc[0][nt][r];
      wk[(size_t)row_g * 64 + col] = (bf16)acc[1][nt][r];
    }
  __syncthreads();
  bf16* Vt = Xs;
#pragma unroll
  for (int nt = 0; nt < 4; ++nt)
#pragma unroll
    for (int r = 0; r < 4; ++r)
      Vt[(nt * 16 + tx) * 72 + (w * 16 + quad * 4 + r)] = (bf16)acc[2][nt][r];
  __syncthreads();
#pragma unroll
  for (int p = 0; p < 2; ++p) {
    int c = tid + p * 256;
    int v = c >> 3, seg = c & 7;
    *(uint4*)&wvt[(size_t)v * kRows + row0 + seg * 8] =
        *(uint4*)&Vt[v * 72 + seg * 8];
  }
}

// ---------------------------------------------------------------------------
// Kernel 2: flash attention — round-2 structure + swizzle ONLY.
// grid 1024: b = bid&7, qb = bid>>3 (16 Q-rows). Block 256 = 4 waves; wave w
// owns 32-key tiles (t*4+w)*32, t<16. Barrier-free main loop, wave-private
// LDS slots, direct global->LDS staging (compiler-scheduled), XOR-swizzled
// chunks (conflict-verified in r5: 2.5e7 -> 2.4e6 cycles).
// LDS 38912 B -> 4 blocks/CU (16 waves/CU).
// ---------------------------------------------------------------------------
__global__ __launch_bounds__(256, 4) void flash_kernel(
    const bf16* __restrict__ wq, const bf16* __restrict__ wk,
    const bf16* __restrict__ wvt, float* __restrict__ vo) {
  const int bid = blockIdx.x;
  const int b = bid & 7, qb = bid >> 3;
  const int q0 = qb * 16;
  const int tid = threadIdx.x;
  const int w = tid >> 6, lane = tid & 63, tx = tid & 15, quad = (tid >> 4) & 3;

  __shared__ __align__(16) char lds[38912];
  bf16* Qs = (bf16*)lds;                        // 16 x 64 (swizzled)
  bf16* Ksw = (bf16*)(lds + 2048 + w * 4096);   // 32 x 64 (swizzled)
  bf16* Vtw = (bf16*)(lds + 18432 + w * 4096);  // 64 x 32 (swizzled)
  bf16* Psw = (bf16*)(lds + 34816 + w * 1024);  // 16 x 32 (swizzled)

  const bf16* wqb = wq + (size_t)(b * kS) * 64;
  const bf16* wkb = wk + (size_t)(b * kS) * 64;
  const bf16* wvb = wvt + b * kS;

  // stage Q (16x64, chunk c -> c^(r&7))
  if (tid < 128) {
    int r = tid >> 3, lc = tid & 7;
    *(uint4*)&Qs[r * 64 + ((lc ^ (r & 7)) * 8)] =
        *(const uint4*)&wqb[(size_t)(q0 + r) * 64 + lc * 8];
  }
  __syncthreads();

  const int kc0 = (quad ^ (tx & 7)) * 8;        // 64-wide rows, s=0 chunk
  const int kc1 = ((4 + quad) ^ (tx & 7)) * 8;  // s=1 chunk
  const int h2 = (tx ^ (tx >> 2)) & 3;          // 32-wide rows keyed by tx

  bf16x8v aq0 = *(bf16x8v*)&Qs[tx * 64 + kc0];
  bf16x8v aq1 = *(bf16x8v*)&Qs[tx * 64 + kc1];

  f32x4 oacc[4];
#pragma unroll
  for (int nt = 0; nt < 4; ++nt) oacc[nt] = (f32x4){0.f, 0.f, 0.f, 0.f};
  float lsum[4] = {0.f, 0.f, 0.f, 0.f};

  const int ksr = lane >> 3, kslc = lane & 7;  // K staging: 8 lanes/row
  const int vsv = lane >> 2, vsck = lane & 3;  // V staging: 4 lanes/v-row

  for (int t = 0; t < 16; ++t) {
    const int k0 = (t * 4 + w) * 32;
    // direct global->LDS staging (round-2 form; compiler batches the loads)
#pragma unroll
    for (int j = 0; j < 4; ++j) {
      int r = ksr + j * 8;
      *(uint4*)&Ksw[r * 64 + ((kslc ^ (r & 7)) * 8)] =
          *(const uint4*)&wkb[(size_t)(k0 + r) * 64 + kslc * 8];
      int v = vsv + j * 16;
      *(uint4*)&Vtw[v * 32 + ((vsck ^ ((v ^ (v >> 2)) & 3)) * 8)] =
          *(const uint4*)&wvb[(size_t)v * kRows + k0 + vsck * 8];
    }

    // QK^T: D[16 q][32 keys]
#pragma unroll
    for (int nt = 0; nt < 2; ++nt) {
      int krow = nt * 16 + tx;
      bf16x8v b0 = *(bf16x8v*)&Ksw[krow * 64 + kc0];
      bf16x8v b1 = *(bf16x8v*)&Ksw[krow * 64 + kc1];
      f32x4 z = (f32x4){0.f, 0.f, 0.f, 0.f};
      z = MFMA16(aq0, b0, z);
      z = MFMA16(aq1, b1, z);
      // no-max softmax numerator + swizzled P store (C-layout -> A-layout)
#pragma unroll
      for (int r = 0; r < 4; ++r) {
        float p = __expf(z[r] * 0.1f);
        lsum[r] += p;
        int q = quad * 4 + r;
        int chunk = nt * 2 + (tx >> 3);
        Psw[q * 32 + ((chunk ^ (r ^ quad)) * 8) + (tx & 7)] = (bf16)p;
      }
    }

    // PV: O[16 q][64 v] += P[16][32] * V[32][64]
    bf16x8v pa = *(bf16x8v*)&Psw[tx * 32 + ((quad ^ h2) * 8)];
#pragma unroll
    for (int nt = 0; nt < 4; ++nt) {
      bf16x8v vb = *(bf16x8v*)&Vtw[(nt * 16 + tx) * 32 + ((quad ^ h2) * 8)];
      oacc[nt] = MFMA16(pa, vb, oacc[nt]);
    }
  }

  // ---- cross-wave combine (round-2 form: private regions, no atomics) ----
  __syncthreads();
  float* myO = (float*)(lds + 2048 + w * 4096);  // 16 x 64 f32 (= Ksw slot)
  float* myL = (float*)(lds + 18432 + w * 64);   // 16 f32
#pragma unroll
  for (int nt = 0; nt < 4; ++nt)
#pragma unroll
    for (int r = 0; r < 4; ++r)
      myO[(quad * 4 + r) * 64 + nt * 16 + tx] = oacc[nt][r];
#pragma unroll
  for (int r = 0; r < 4; ++r) {
    float v = lsum[r];
#pragma unroll
    for (int m = 1; m < 16; m <<= 1) v += __shfl_xor(v, m, 64);
    if (tx == 0) myL[quad * 4 + r] = v;
  }
  __syncthreads();

#pragma unroll
  for (int p = 0; p < 4; ++p) {
    int e = tid + p * 256;  // 1024: 16 rows x 64 cols
    int row = e >> 6;
    float s = 0.f, lt = 0.f;
#pragma unroll
    for (int wv = 0; wv < 4; ++wv) {
      s += ((const float*)(lds + 2048 + wv * 4096))[e];
      lt += ((const float*)(lds + 18432 + wv * 64))[row];
    }
    vo[(size_t)(b * kS + q0 + row) * 64 + (e & 63)] = s / lt;
  }
}

// ---------------------------------------------------------------------------
// Kernel 3: out = vo [16384,64] @ dr [64,512], fp32 (r1/r2's validated kernel).
// ---------------------------------------------------------------------------
__global__ __launch_bounds__(256) void out_gemm_kernel(
    const float* __restrict__ v, const float* __restrict__ dr,
    float* __restrict__ out) {
  const int rt = blockIdx.x, ct = blockIdx.y;
  const int tid = threadIdx.x;
  const int tx = tid & 15, ty = tid >> 4;

  __shared__ float As[64][68];
  __shared__ float Bs[64][68];

#pragma unroll
  for (int p = 0; p < 4; ++p) {
    int f4 = tid + p * 256;
    int r = f4 >> 4, c = (f4 & 15) * 4;
    *(float4*)&As[r][c] = *(const float4*)(v + (size_t)(rt * 64 + r) * kH + c);
    *(float4*)&Bs[r][c] = *(const float4*)(dr + (size_t)r * kD + ct * 64 + c);
  }
  __syncthreads();

  float acc[4][4] = {};
#pragma unroll
  for (int k = 0; k < 64; k += 4) {
    float a[4][4], bb[4][4];
#pragma unroll
    for (int i = 0; i < 4; ++i) {
      float4 t = *(const float4*)&As[ty * 4 + i][k];
      a[i][0] = t.x; a[i][1] = t.y; a[i][2] = t.z; a[i][3] = t.w;
    }
#pragma unroll
    for (int kk = 0; kk < 4; ++kk) {
      float4 t = *(const float4*)&Bs[k + kk][tx * 4];
      bb[kk][0] = t.x; bb[kk][1] = t.y; bb[kk][2] = t.z; bb[kk][3] = t.w;
    }
#pragma unroll
    for (int i = 0; i < 4; ++i)
#pragma unroll
      for (int kk = 0; kk < 4; ++kk)
#pragma unroll
        for (int j = 0; j < 4; ++j)
          acc[i][j] = fmaf(a[i][kk], bb[kk][j], acc[i][j]);
  }
#pragma unroll
  for (int i = 0; i < 4; ++i) {
    float4 vv = make_float4(acc[i][0], acc[i][1], acc[i][2], acc[i][3]);
    *(float4*)(out + (size_t)(rt * 64 + ty * 4 + i) * kD + ct * 64 + tx * 4) = vv;
  }
}

extern "C" void kernel_launch(void* const* d_in, const int* in_sizes, int n_in,
                              void* d_out, int out_size, void* d_ws,
                              size_t ws_size, hipStream_t stream) {
  const float* x = (const float*)d_in[0];      // [8,2048,512]
  const float* w = (const float*)d_in[1];      // [3,512,64]
  const float* dense = (const float*)d_in[2];  // [512,512]
  float* out = (float*)d_out;                  // [8,2048,512] fp32

  bf16* wq = (bf16*)d_ws;                // 1,048,576 bf16
  bf16* wk = wq + (size_t)kRows * 64;    // 1,048,576
  bf16* wvt = wk + (size_t)kRows * 64;   // 1,048,576  [64][16384]
  bf16* wtg = wvt + (size_t)kRows * 64;  // 98,304     [3][64][512]
  float* dr = (float*)(wtg + 98304);     // 32,768 f32 [64][512]
  float* vo = dr + 32768;                // 1,048,576 f32

  prep_kernel<<<512, 256, 0, stream>>>(w, dense, wtg, dr);
  proj_kernel<<<256, 256, 0, stream>>>(x, wtg, wq, wk, wvt);
  flash_kernel<<<1024, 256, 0, stream>>>(wq, wk, wvt, vo);
  out_gemm_kernel<<<dim3(kRows / 64, kD / 64), 256, 0, stream>>>(vo, dr, out);
}